// Round 7
// baseline (311.076 us; speedup 1.0000x reference)
//
#include <hip/hip_runtime.h>
#include <hip/hip_bf16.h>
#include <stdint.h>

// ---------------------------------------------------------------------------
// HeadAttention: Q=xq*W^T+b, K=xk*W^T+b, V=xv*W^T+b (same W,b),
// O = softmax(causal(Q K^T / 32)) V.    B=4, S=2048, E=1024, fp32 in/out.
// R12 = R11 qkv/cvt (best measured: 91 us, 0 conflicts) + scores/pv
// re-gridded for TLP: 2-wave 128-thread blocks on 64x128 tiles.
//   scores: 1088 exact lower-tri blocks (4.25/CU, was 2.1) -- no dead blocks,
//           per-XCD contiguous gid range (A-tile reused across consecutive cn)
//   pv:     1024 blocks (4/CU, was 2), per-XCD rm-pair balance {x, 15-x}
// Inner loop identical to R11: zero-conflict [rows][64] swizzled LDS
// (chunk c of row r at slot c^(r&7); linear global_load_lds dest +
// inverse-swizzled source), 2-barrier __syncthreads K-loop.
// ---------------------------------------------------------------------------

typedef __attribute__((ext_vector_type(8))) short bf16x8;
typedef __attribute__((ext_vector_type(4))) float floatx4;

#define DEVI static __device__ __forceinline__

static constexpr int S_ = 2048;
static constexpr int E_ = 1024;
static constexpr int BATCH = 4;
static constexpr int N4X = 8192 * 1024 / 4;  // float4 count per X input

DEVI unsigned short f2b(float f) {
  union { float f; unsigned u; } v; v.f = f;
  return (unsigned short)((v.u + 0x7FFFu + ((v.u >> 16) & 1u)) >> 16); // RNE
}

DEVI void async_load16(const void* g, void* l) {
  __builtin_amdgcn_global_load_lds(
      (__attribute__((address_space(1))) void*)(void*)(g),
      (__attribute__((address_space(3))) void*)(l),
      16, 0, 0);
}

// ---- zero-conflict [ROWS][64] tile machinery (measured 0-conflict) --------

// stage a ROWSx64 bf16 tile with NTHR threads (16B per load).  LDS dest is
// linear (global_load_lds requirement); the 16B chunk at linear slot s of
// row r holds logical chunk s ^ (r&7) (source inverse-swizzled).
template <int ROWS, int NTHR>
DEVI void stage64(const unsigned short* __restrict__ src, unsigned short* ls,
                  int ld, int tid) {
#pragma unroll
  for (int j = 0; j < ROWS * 8 / NTHR; ++j) {
    const int u = tid + j * NTHR;
    const int row = u >> 3, slot = u & 7;
    async_load16(src + (size_t)row * ld + ((slot ^ (row & 7)) << 3),
                 ls + u * 8);
  }
}

// read logical (row r, k-chunk c in [0,8)) from a swizzled [ROWS][64] tile
DEVI bf16x8 ldfrag64(const unsigned short* ls, int r, int c) {
  return *(const bf16x8*)(ls + r * 64 + ((c ^ (r & 7)) << 3));
}

// 32 MFMAs on one staged 64-K A/B tile pair (two 32-K halves).
DEVI void mfma_tile64(const unsigned short* lsA, const unsigned short* lsB,
                      int m0, int n0, int lrow, int g, floatx4 (&acc)[4][4]) {
#pragma unroll
  for (int ks = 0; ks < 2; ++ks) {
    bf16x8 af[4], bfr[4];
#pragma unroll
    for (int i = 0; i < 4; ++i)
      af[i] = ldfrag64(lsA, m0 + i * 16 + lrow, ks * 4 + g);
#pragma unroll
    for (int i = 0; i < 4; ++i)
      bfr[i] = ldfrag64(lsB, n0 + i * 16 + lrow, ks * 4 + g);
#pragma unroll
    for (int mi = 0; mi < 4; ++mi)
#pragma unroll
      for (int ni = 0; ni < 4; ++ni)
        acc[mi][ni] = __builtin_amdgcn_mfma_f32_16x16x32_bf16(
            af[mi], bfr[ni], acc[mi][ni], 0, 0, 0);
  }
}

// fp32 -> bf16 convert: xq|xk|xv -> Xb, Wq -> Wb, one dispatch
__global__ void cvt_all(const float* __restrict__ xq,
                        const float* __restrict__ xk,
                        const float* __restrict__ xv,
                        const float* __restrict__ Wq,
                        unsigned short* __restrict__ Xb,
                        unsigned short* __restrict__ Wb) {
  int i = blockIdx.x * blockDim.x + threadIdx.x;
  const float4* src;
  ushort4* dst;
  if (i < 3 * N4X) {
    int seg = i / N4X, off = i - seg * N4X;
    const float* s = (seg == 0) ? xq : (seg == 1) ? xk : xv;
    src = (const float4*)s + off;
    dst = (ushort4*)(Xb + (size_t)seg * 8192 * 1024) + off;
  } else {
    int off = i - 3 * N4X;  // [0, 1024*1024/4)
    src = (const float4*)Wq + off;
    dst = (ushort4*)Wb + off;
  }
  float4 v = *src;
  ushort4 o;
  o.x = f2b(v.x); o.y = f2b(v.y); o.z = f2b(v.z); o.w = f2b(v.w);
  *dst = o;
}

// ---------------------------------------------------------------------------
// Fused QKV linear (R11 verbatim): C = Xb * Wb^T + bias.  Xb = [3*8192,1024].
// 1536 blocks; XCD swizzle: 8 bn sharing an A-tile at stride-8 => same XCD
// L2.  V (input 2) stored transposed: Vt[b][e][s].
// ---------------------------------------------------------------------------
__global__ __launch_bounds__(256) void gemm_qkv(
    const unsigned short* __restrict__ Xb, const unsigned short* __restrict__ Wb,
    const float* __restrict__ bias, unsigned short* __restrict__ Qb,
    unsigned short* __restrict__ Kb, unsigned short* __restrict__ Vt) {
  __shared__ __align__(16) unsigned short lsA[128 * 64];
  __shared__ __align__(16) unsigned short lsB[128 * 64];
  const int l = blockIdx.x;
  const int xcd = l & 7, i = l >> 3;
  const int bn = i & 7;
  const int bmg = xcd * 24 + (i >> 3);  // [0,192): global 128-row tile
  const int input = bmg / 64, bm = bmg % 64;
  const unsigned short* A = Xb + (size_t)bmg * 128 * 1024;
  const unsigned short* W = Wb + (size_t)bn * 128 * 1024;

  const int tid = threadIdx.x;
  const int lane = tid & 63, wave = tid >> 6;
  const int m0 = (wave >> 1) * 64, n0 = (wave & 1) * 64;
  const int lrow = lane & 15, g = lane >> 4;

  floatx4 acc[4][4] = {};
  for (int kt = 0; kt < 16; ++kt) {  // 16 barriers, 64 K each
    if (kt) __syncthreads();
    stage64<128, 256>(A + kt * 64, lsA, 1024, tid);
    stage64<128, 256>(W + kt * 64, lsB, 1024, tid);
    __syncthreads();
    mfma_tile64(lsA, lsB, m0, n0, lrow, g, acc);
  }

  unsigned short* C = (input == 0) ? Qb : (input == 1) ? Kb : Vt;
  const int rb = (lane >> 4) * 4;  // C/D: col=lane&15, row=(lane>>4)*4+reg
#pragma unroll
  for (int mi = 0; mi < 4; ++mi)
#pragma unroll
    for (int ni = 0; ni < 4; ++ni) {
      int gcol = bn * 128 + n0 + ni * 16 + lrow;
      float bv = bias[gcol];
#pragma unroll
      for (int r = 0; r < 4; ++r) {
        int grow = bm * 128 + m0 + mi * 16 + rb + r;
        unsigned short val = f2b(acc[mi][ni][r] + bv);
        if (input == 2) {
          int b = grow >> 11, s = grow & 2047;
          C[((size_t)b * 1024 + gcol) * 2048 + s] = val;
        } else {
          C[(size_t)grow * 1024 + gcol] = val;
        }
      }
    }
}

// ---------------------------------------------------------------------------
// Scores+exp: P[z][q,k] = exp(Q.K/32) (unnorm, bf16; 0 where k>q), and
// l[z*2048+q] += row sums (atomic).  64-row x 128-col tiles, lower-tri only:
// per batch sum_{rm<32}((rm>>1)+1) = 272 blocks, total 1088 (4.25/CU).
// 2 waves (128 thr): wave w covers cols n0=w*64, all 64 rows.
// gid = (l&7)*136 + l>>3: each XCD gets a contiguous range (A-tile reused
// across consecutive cn; each batch spans exactly 2 XCDs).
// ---------------------------------------------------------------------------
__global__ __launch_bounds__(128) void gemm_scores_exp(
    const unsigned short* __restrict__ Qb,
    const unsigned short* __restrict__ Kb, unsigned short* __restrict__ P,
    float* __restrict__ lsum) {
  __shared__ __align__(16) unsigned short lsA[64 * 64];
  __shared__ __align__(16) unsigned short lsB[128 * 64];
  const int l = blockIdx.x;
  const int gid = (l & 7) * 136 + (l >> 3);  // [0,1088)
  const int z = gid >> 8 >= 0 ? gid / 272 : 0;
  int r = gid % 272;
  int rm = 0;
  for (;;) { const int c = (rm >> 1) + 1; if (r < c) break; r -= c; ++rm; }
  const int cn = r;  // [0, rm>>1]

  const unsigned short* A = Qb + ((size_t)z * S_ + rm * 64) * E_;
  const unsigned short* Bt = Kb + ((size_t)z * S_ + cn * 128) * E_;
  const int tid = threadIdx.x;
  const int lane = tid & 63, wave = tid >> 6;
  const int n0 = wave * 64;
  const int lrow = lane & 15, g = lane >> 4;

  floatx4 acc[4][4] = {};
  for (int kt = 0; kt < 16; ++kt) {
    if (kt) __syncthreads();
    stage64<64, 128>(A + kt * 64, lsA, E_, tid);
    stage64<128, 128>(Bt + kt * 64, lsB, E_, tid);
    __syncthreads();
    mfma_tile64(lsA, lsB, 0, n0, lrow, g, acc);
  }

  const int rb = (lane >> 4) * 4;
  const bool diag = (cn == (rm >> 1));
#pragma unroll
  for (int mi = 0; mi < 4; ++mi)
#pragma unroll
    for (int r2 = 0; r2 < 4; ++r2) {
      const int grow = rm * 64 + mi * 16 + rb + r2;
      float rsum = 0.f;
#pragma unroll
      for (int ni = 0; ni < 4; ++ni) {
        const int gcol = cn * 128 + n0 + ni * 16 + lrow;
        float p = __expf(acc[mi][ni][r2] * 0.03125f);
        if (diag && gcol > grow) p = 0.f;
        P[((size_t)z * S_ + grow) * S_ + gcol] = f2b(p);
        rsum += p;
      }
      // reduce over the 16 lanes holding this row's 64 columns
#pragma unroll
      for (int off = 1; off < 16; off <<= 1) rsum += __shfl_xor(rsum, off);
      if ((lane & 15) == 0) atomicAdd(&lsum[z * S_ + grow], rsum);
    }
}

// ---------------------------------------------------------------------------
// PV: out[z][q,e] = (P V) / l[q].  64-row x 128-col tiles, 1024 blocks
// (4/CU).  K truncated: NT = ((rm>>1)+1)*2 64-K steps.  Per-XCD balance:
// xcd x handles rm-pairs {x, 15-x} (per (z,bn): 2(x+1) + 2(16-x) = 34 steps).
//   i = l>>3 in [0,128): z=i>>5, bn=(i>>2)&7, s=i&3;
//   pm = (s&1) ? xcd : 15-xcd; rm = 2*pm + (s>>1).
// ---------------------------------------------------------------------------
__global__ __launch_bounds__(128) void gemm_pv(
    const unsigned short* __restrict__ Pb,
    const unsigned short* __restrict__ Vt, const float* __restrict__ lsum,
    float* __restrict__ Out) {
  __shared__ __align__(16) unsigned short lsA[64 * 64];
  __shared__ __align__(16) unsigned short lsB[128 * 64];
  const int l = blockIdx.x;
  const int xcd = l & 7, i = l >> 3;
  const int z = i >> 5, bn = (i >> 2) & 7, s = i & 3;
  const int pm = (s & 1) ? xcd : 15 - xcd;
  const int rm = 2 * pm + (s >> 1);  // [0,32)

  const unsigned short* A = Pb + ((size_t)z * S_ + rm * 64) * S_;
  const unsigned short* Bt = Vt + ((size_t)z * E_ + bn * 128) * S_;
  float* C = Out + (size_t)z * S_ * E_;
  const int tid = threadIdx.x;
  const int lane = tid & 63, wave = tid >> 6;
  const int n0 = wave * 64;
  const int lrow = lane & 15, g = lane >> 4;

  floatx4 acc[4][4] = {};
  const int NT = ((rm >> 1) + 1) * 2;  // 64-K steps, covers all causal k
  for (int kt = 0; kt < NT; ++kt) {
    if (kt) __syncthreads();
    stage64<64, 128>(A + kt * 64, lsA, S_, tid);
    stage64<128, 128>(Bt + kt * 64, lsB, S_, tid);
    __syncthreads();
    mfma_tile64(lsA, lsB, 0, n0, lrow, g, acc);
  }

  const int rb = (lane >> 4) * 4;
#pragma unroll
  for (int mi = 0; mi < 4; ++mi)
#pragma unroll
    for (int r2 = 0; r2 < 4; ++r2) {
      const int grow = rm * 64 + mi * 16 + rb + r2;
      const float inv = 1.0f / lsum[z * S_ + grow];
#pragma unroll
      for (int ni = 0; ni < 4; ++ni) {
        const int gcol = bn * 128 + n0 + ni * 16 + lrow;
        C[(size_t)grow * E_ + gcol] = acc[mi][ni][r2] * inv;
      }
    }
}

// ---------------------------------------------------------------------------
extern "C" void kernel_launch(void* const* d_in, const int* in_sizes, int n_in,
                              void* d_out, int out_size, void* d_ws,
                              size_t ws_size, hipStream_t stream) {
  (void)in_sizes; (void)n_in; (void)out_size; (void)ws_size;
  const float* xq = (const float*)d_in[0];
  const float* xk = (const float*)d_in[1];
  const float* xv = (const float*)d_in[2];
  const float* Wq = (const float*)d_in[3];
  const float* bq = (const float*)d_in[4];
  // d_in[5] att_mask: exact triu(k=1) causal mask, handled analytically.
  float* out = (float*)d_out;

  // workspace (<= 114 MB used):
  //  [0,48M):  Xb (bf16 3*8192*1024) during cvt+QKV; then reused as
  //            P (bf16 4*2048*2048 = 32M) by scores/pv.
  //  [48,50M): Wb  [50,66M): Qb  [66,82M): Kb  [82,98M): Vt
  //  [98M, 98M+32K): l (fp32 row sums)
  unsigned short* base16 = (unsigned short*)d_ws;
  unsigned short* Xb = base16;
  unsigned short* P = base16;
  unsigned short* Wb = base16 + (size_t)24 * 1024 * 1024;  // +48MB
  unsigned short* Qb = Wb + (size_t)1024 * 1024;
  unsigned short* Kb = Qb + (size_t)8192 * 1024;
  unsigned short* Vt = Kb + (size_t)8192 * 1024;
  float* lsum = (float*)(Vt + (size_t)8192 * 1024);  // +98MB, 32KB

  hipMemsetAsync(lsum, 0, BATCH * S_ * sizeof(float), stream);

  const int n4tot = 3 * N4X + 1024 * 1024 / 4;
  cvt_all<<<n4tot / 256, 256, 0, stream>>>(xq, xk, xv, Wq, Xb, Wb);

  gemm_qkv<<<1536, 256, 0, stream>>>(Xb, Wb, bq, Qb, Kb, Vt);
  gemm_scores_exp<<<1088, 128, 0, stream>>>(Qb, Kb, P, lsum);
  gemm_pv<<<1024, 128, 0, stream>>>(P, Vt, lsum, out);
}